// Round 1
// baseline (1564.805 us; speedup 1.0000x reference)
//
#include <hip/hip_runtime.h>

typedef float f32x4 __attribute__((ext_vector_type(4)));
typedef float f32x16 __attribute__((ext_vector_type(16)));
typedef int i32x4v __attribute__((ext_vector_type(4)));
typedef int i32x8v __attribute__((ext_vector_type(8)));
typedef unsigned char uchar;
typedef long i64;

#define KEPS 1e-8f
#define BM 128
#define BN 128
#define BK 64    // fp8 bytes == elements; 16 K-iterations over D=1024

// ---------------- 1) row L2-normalize: fp32 norms + fp8 e4m3 copy -----------
__global__ __launch_bounds__(256) void k_normalize(
    const float* __restrict__ in, uchar* __restrict__ xq,
    float* __restrict__ norms, unsigned long long* __restrict__ best,
    float* __restrict__ psum, int D)
{
    const int row = blockIdx.x;
    const int t = threadIdx.x;
    const float4* inr = (const float4*)(in + (size_t)row * D);
    float4 v = inr[t];                       // D=1024 -> 256 float4
    float ss = v.x*v.x + v.y*v.y + v.z*v.z + v.w*v.w;
    for (int off = 32; off; off >>= 1) ss += __shfl_down(ss, off);
    __shared__ float red[4];
    const int lane = t & 63, wave = t >> 6;
    if (lane == 0) red[wave] = ss;
    __syncthreads();
    const float total = red[0] + red[1] + red[2] + red[3];
    const float nrm = sqrtf(total);
    const float inv = 1.0f / fmaxf(nrm, KEPS);
    unsigned r = 0;
    r = __builtin_amdgcn_cvt_pk_fp8_f32(v.x * inv, v.y * inv, r, 0);
    r = __builtin_amdgcn_cvt_pk_fp8_f32(v.z * inv, v.w * inv, r, 1);
    ((unsigned*)(xq + (size_t)row * D))[t] = r;
    if (t == 0) {
        norms[row] = nrm;
        best[row] = 0ull;                    // any real packed key beats 0
    }
    if (row < 256 && t == 1) psum[row * 16] = 0.0f;   // cache-line-padded partials
}

__device__ __forceinline__ unsigned long long pack_key(float v, unsigned idx)
{
    unsigned ub = __float_as_uint(v);
    ub = (ub & 0x80000000u) ? ~ub : (ub | 0x80000000u); // monotonic map
    return ((unsigned long long)ub << 32) | (unsigned long long)(~idx);
}

// ---------------- 2) x x^T triangular fp8 GEMM, dbuf LDS, 4 blocks/CU -------
// BM=BN=128, BK=64, 4 waves in 2x2, each wave owns 64x64.
// NEW (this round): MFMA switched from 16x16x32_fp8_fp8 (bf16-rate pipe,
// ~2.2 PF) to the block-scaled mfma_scale_f32_32x32x64_f8f6f4 with unit
// scales (e8m0=127 -> 2^0), which runs on the 2x-rate MX pipe (~4.7 PF)
// with IDENTICAL numerics. Per K-step/wave: 4 MFMA (was 32) and
// 8x ds_read_b128 (was 16x ds_read_b64).
// Fragment layout (assumed, verified by harness): A/B lane l holds
// row/col (l&31), k-bytes [(l>>5)*32, +32) => chunks {2h, 2h+1} of the
// 64B row; C/D: col=lane&31, row=(reg&3)+8*(reg>>2)+4*(lane>>5).
// XOR chunk swizzle (row ^ row>>2)&3 kept: staging stays lane-contiguous
// (swizzle applied to the *global* column); for b128 reads each 16-lane
// phase spreads over 8 bank-groups at 2 lanes/group (free 2-way).
__global__ __launch_bounds__(256, 4) void k_gemm_argmax(
    const uchar* __restrict__ xq, unsigned long long* __restrict__ best,
    int T)
{
    // triangular mapping: p -> (by, bx), bx >= by
    const int p = blockIdx.x;
    const float tf = (float)T + 0.5f;
    int by = (int)(tf - sqrtf(tf * tf - 2.0f * (float)p));
    while (by > 0 && p < by * T - by * (by - 1) / 2) --by;
    while (p >= (by + 1) * T - (by + 1) * by / 2) ++by;
    const int bx = by + (p - (by * T - by * (by - 1) / 2));

    __shared__ uchar lds[2][(BM + BN) * BK];   // 2 x 16 KiB
    const int t    = threadIdx.x;
    const int lane = t & 63;
    const int wave = t >> 6;
    const int r5   = lane & 31;              // row-within-32
    const int h    = lane >> 5;              // k-half selector
    const int wrow = (wave >> 1) * 64;
    const int wcol = (wave & 1) * 64;
    const int m0   = by * BM;
    const int n0   = bx * BN;

    f32x16 acc[2][2] = {};

    // staging: thread t owns stored chunk c = t (rows 0..63) and c = t + 256
    // (rows 64..127) of each panel; stored col = t&3, global col swizzled.
    const int row_s = t >> 2;
    const int col_s = t & 3;
    const int gsw = (col_s ^ ((row_s ^ (row_s >> 2)) & 3)) * 16;  // byte col
    // note swz(row+64) == swz(row), so the same gsw serves both halves
    const uchar* aP0 = xq + (size_t)(m0 + row_s) * 1024 + gsw;
    const uchar* bP0 = xq + (size_t)(n0 + row_s) * 1024 + gsw;
    const uchar* aP1 = aP0 + 64 * 1024;
    const uchar* bP1 = bP0 + 64 * 1024;
    const int l16 = t * 16;

#define STAGE(buf, koff)                                                              \
    do {                                                                              \
        __builtin_amdgcn_global_load_lds(                                             \
            (const __attribute__((address_space(1))) void*)(aP0 + (koff)),            \
            (__attribute__((address_space(3))) void*)(&lds[buf][0] + l16), 16, 0, 0); \
        __builtin_amdgcn_global_load_lds(                                             \
            (const __attribute__((address_space(1))) void*)(aP1 + (koff)),            \
            (__attribute__((address_space(3))) void*)(&lds[buf][4096] + l16), 16, 0, 0); \
        __builtin_amdgcn_global_load_lds(                                             \
            (const __attribute__((address_space(1))) void*)(bP0 + (koff)),            \
            (__attribute__((address_space(3))) void*)(&lds[buf][8192] + l16), 16, 0, 0); \
        __builtin_amdgcn_global_load_lds(                                             \
            (const __attribute__((address_space(1))) void*)(bP1 + (koff)),            \
            (__attribute__((address_space(3))) void*)(&lds[buf][12288] + l16), 16, 0, 0); \
    } while (0)

    STAGE(0, 0);
    __syncthreads();

    // lane-constant LDS read offsets.
    // perm(row) for row = wrow + i*32 + r5 reduces to (r5 ^ (r5>>2)) & 3
    // (wrow, i*32 are multiples of 32 -> drop out of both XOR terms).
    const int psw = (r5 ^ (r5 >> 2)) & 3;
    const int c0  = ((2 * h + 0) ^ psw) * 16;   // first 16B chunk (swizzled)
    const int c1  = ((2 * h + 1) ^ psw) * 16;   // second 16B chunk (swizzled)
    const int aoff0 = (wrow +      r5) * 64;
    const int aoff1 = (wrow + 32 + r5) * 64;
    const int boff0 = (wcol +      r5) * 64;
    const int boff1 = (wcol + 32 + r5) * 64;

    #pragma unroll
    for (int kt = 0; kt < 16; ++kt) {
        const int cur = kt & 1;
        if (kt < 15) STAGE(cur ^ 1, (kt + 1) * BK);   // K-advance in pointer
        const uchar* Al = &lds[cur][0];
        const uchar* Bl = &lds[cur][8192];

        i32x8v bfr[2];
        {
            i32x4v lo0 = *(const i32x4v*)(Bl + boff0 + c0);
            i32x4v hi0 = *(const i32x4v*)(Bl + boff0 + c1);
            bfr[0] = __builtin_shufflevector(lo0, hi0, 0, 1, 2, 3, 4, 5, 6, 7);
            i32x4v lo1 = *(const i32x4v*)(Bl + boff1 + c0);
            i32x4v hi1 = *(const i32x4v*)(Bl + boff1 + c1);
            bfr[1] = __builtin_shufflevector(lo1, hi1, 0, 1, 2, 3, 4, 5, 6, 7);
        }
        #pragma unroll
        for (int i = 0; i < 2; ++i) {
            const uchar* ap = Al + (i ? aoff1 : aoff0);
            i32x4v lo = *(const i32x4v*)(ap + c0);
            i32x4v hi = *(const i32x4v*)(ap + c1);
            i32x8v af = __builtin_shufflevector(lo, hi, 0, 1, 2, 3, 4, 5, 6, 7);
            acc[i][0] = __builtin_amdgcn_mfma_scale_f32_32x32x64_f8f6f4(
                af, bfr[0], acc[i][0], 0, 0, 0, 0x7F, 0, 0x7F);
            acc[i][1] = __builtin_amdgcn_mfma_scale_f32_32x32x64_f8f6f4(
                af, bfr[1], acc[i][1], 0, 0, 0, 0x7F, 0, 0x7F);
        }
        __syncthreads();
    }
#undef STAGE

    // ---- row-wise argmax (this wave's 64 rows, over its 64 cols) ----
    // C/D 32x32 layout: col = lane&31, row = (reg&3) + 8*(reg>>2) + 4*(lane>>5)
    #pragma unroll
    for (int i = 0; i < 2; ++i) {
        #pragma unroll
        for (int r = 0; r < 16; ++r) {
            const int rin  = (r & 3) + 8 * (r >> 2) + 4 * h;
            const int grow = m0 + wrow + i * 32 + rin;
            float v = -3.0f; unsigned c = 0xFFFFFFFFu;
            #pragma unroll
            for (int j = 0; j < 2; ++j) {
                const int col = n0 + wcol + j * 32 + r5;
                const float val = acc[i][j][r];
                if (col != grow && (val > v || (val == v && (unsigned)col < c))) {
                    v = val; c = (unsigned)col;
                }
            }
            // reduce across the 32 lanes of this half-wave (same row)
            for (int off = 16; off; off >>= 1) {
                const float    ov = __shfl_xor(v, off);
                const unsigned oc = (unsigned)__shfl_xor((int)c, off);
                if (ov > v || (ov == v && oc < c)) { v = ov; c = oc; }
            }
            if (r5 == 0) atomicMax(best + grow, pack_key(v, c));
        }
    }

    // ---- col-wise argmax (off-diagonal blocks only) ----
    if (bx != by) {
        #pragma unroll
        for (int j = 0; j < 2; ++j) {
            const int gcol = n0 + wcol + j * 32 + r5;
            float v = -3.0f; unsigned c = 0xFFFFFFFFu;
            #pragma unroll
            for (int i = 0; i < 2; ++i) {
                #pragma unroll
                for (int r = 0; r < 16; ++r) {
                    const int grow = m0 + wrow + i * 32
                                   + (r & 3) + 8 * (r >> 2) + 4 * h;
                    const float val = acc[i][j][r];
                    if (val > v || (val == v && (unsigned)grow < c)) {
                        v = val; c = (unsigned)grow;
                    }
                }
            }
            // merge the two half-waves (same col set, different rows)
            {
                const float    ov = __shfl_xor(v, 32);
                const unsigned oc = (unsigned)__shfl_xor((int)c, 32);
                if (ov > v || (ov == v && oc < c)) { v = ov; c = oc; }
            }
            if (h == 0) atomicMax(best + gcol, pack_key(v, c));
        }
    }
}

// ---------------- 3) pairwise distance + log -> 256 padded partials ---------
__global__ __launch_bounds__(256) void k_dist(
    const float* __restrict__ in, const float* __restrict__ norms,
    const unsigned long long* __restrict__ best, float* __restrict__ psum, int D)
{
    const int row = blockIdx.x;
    const int t = threadIdx.x;
    const unsigned long long key = best[row];
    const int nb = (int)(~(unsigned)key);        // recover neighbor index
    const float invi = 1.0f / fmaxf(norms[row], KEPS);
    const float invj = 1.0f / fmaxf(norms[nb], KEPS);
    const float4* xi = (const float4*)(in + (size_t)row * D);
    const float4* xj = (const float4*)(in + (size_t)nb * D);
    const float4 a = xi[t], b = xj[t];
    const float dx = a.x * invi - b.x * invj + KEPS;
    const float dy = a.y * invi - b.y * invj + KEPS;
    const float dz = a.z * invi - b.z * invj + KEPS;
    const float dw = a.w * invi - b.w * invj + KEPS;
    float ss = dx*dx + dy*dy + dz*dz + dw*dw;
    for (int off = 32; off; off >>= 1) ss += __shfl_down(ss, off);
    __shared__ float red[4];
    const int lane = t & 63, wave = t >> 6;
    if (lane == 0) red[wave] = ss;
    __syncthreads();
    if (t == 0) {
        const float tot = red[0] + red[1] + red[2] + red[3];
        // scatter over 256 cache-line-padded slots: 64 atomics/slot, no hotspot
        atomicAdd(psum + (row & 255) * 16, logf(sqrtf(tot) + KEPS));
    }
}

// ---------------- 4) finalize: reduce 256 partials --------------------------
__global__ void k_final(const float* __restrict__ psum, float* __restrict__ out, float invN)
{
    const int t = threadIdx.x;                   // 64 threads
    float s = psum[t * 16] + psum[(t + 64) * 16]
            + psum[(t + 128) * 16] + psum[(t + 192) * 16];
    for (int off = 32; off; off >>= 1) s += __shfl_down(s, off);
    if (t == 0) out[0] = -s * invN;
}

extern "C" void kernel_launch(void* const* d_in, const int* in_sizes, int n_in,
                              void* d_out, int out_size, void* d_ws, size_t ws_size,
                              hipStream_t stream)
{
    const float* in = (const float*)d_in[0];
    const int D = 1024;
    const int N = in_sizes[0] / D;               // 16384

    char* ws = (char*)d_ws;
    uchar* xq = (uchar*)ws;                                      // N*D = 16 MiB
    size_t off = (size_t)N * D;
    float* norms = (float*)(ws + off);           off += (size_t)N * 4;
    unsigned long long* best = (unsigned long long*)(ws + off); off += (size_t)N * 8;
    float* psum = (float*)(ws + off);            // 256 slots x 16 floats
    float* out = (float*)d_out;

    k_normalize<<<N, 256, 0, stream>>>(in, xq, norms, best, psum, D);
    const int T = N / BM;                        // 128 tiles per dim
    const int P = T * (T + 1) / 2;               // 8256 upper-tri blocks
    k_gemm_argmax<<<P, 256, 0, stream>>>(xq, best, T);
    k_dist<<<N, 256, 0, stream>>>(in, norms, best, psum, D);
    k_final<<<1, 64, 0, stream>>>(psum, out, 1.0f / (float)N);
}

// Round 2
// 1303.457 us; speedup vs baseline: 1.2005x; 1.2005x over previous
//
#include <hip/hip_runtime.h>

typedef float f32x4 __attribute__((ext_vector_type(4)));
typedef float f32x16 __attribute__((ext_vector_type(16)));
typedef int i32x4v __attribute__((ext_vector_type(4)));
typedef int i32x8v __attribute__((ext_vector_type(8)));
typedef unsigned char uchar;
typedef long i64;

#define KEPS 1e-8f
#define BM 128
#define BN 128
#define BK 64    // fp8 bytes == elements; 16 K-iterations over D=1024

// ---------------- 1) row L2-normalize: fp32 norms + fp8 e4m3 copy -----------
__global__ __launch_bounds__(256) void k_normalize(
    const float* __restrict__ in, uchar* __restrict__ xq,
    float* __restrict__ norms, unsigned long long* __restrict__ best,
    float* __restrict__ psum, int D)
{
    const int row = blockIdx.x;
    const int t = threadIdx.x;
    const float4* inr = (const float4*)(in + (size_t)row * D);
    float4 v = inr[t];                       // D=1024 -> 256 float4
    float ss = v.x*v.x + v.y*v.y + v.z*v.z + v.w*v.w;
    for (int off = 32; off; off >>= 1) ss += __shfl_down(ss, off);
    __shared__ float red[4];
    const int lane = t & 63, wave = t >> 6;
    if (lane == 0) red[wave] = ss;
    __syncthreads();
    const float total = red[0] + red[1] + red[2] + red[3];
    const float nrm = sqrtf(total);
    const float inv = 1.0f / fmaxf(nrm, KEPS);
    unsigned r = 0;
    r = __builtin_amdgcn_cvt_pk_fp8_f32(v.x * inv, v.y * inv, r, 0);
    r = __builtin_amdgcn_cvt_pk_fp8_f32(v.z * inv, v.w * inv, r, 1);
    ((unsigned*)(xq + (size_t)row * D))[t] = r;
    if (t == 0) {
        norms[row] = nrm;
        best[row] = 0ull;                    // any real packed key beats 0
    }
    if (row < 256 && t == 1) psum[row * 16] = 0.0f;   // cache-line-padded partials
}

__device__ __forceinline__ unsigned long long pack_key(float v, unsigned idx)
{
    unsigned ub = __float_as_uint(v);
    ub = (ub & 0x80000000u) ? ~ub : (ub | 0x80000000u); // monotonic map
    return ((unsigned long long)ub << 32) | (unsigned long long)(~idx);
}

// ---------------- 2) x x^T triangular fp8 GEMM, dbuf LDS, MX-rate MFMA ------
// BM=BN=128, BK=64, 4 waves in 2x2, each wave owns 64x64 as 2x2 of 32x32.
// mfma_scale_f32_32x32x64_f8f6f4 with unit scales (e8m0=127 -> 2^0): 2x-rate
// MX pipe, numerically identical to plain fp8 MFMA. Layouts verified by the
// round-1 harness run (passed=true).
// ROUND-2 FIX: __launch_bounds__(256,4) capped the unified reg file at
// ~128/wave; the f32x16 acc[2][2] (64) + a/b fragments (24) + staging
// addresses (~50) => ~140-150 demand. Compiler spilled the accumulators to
// scratch: WRITE_SIZE 82MB->3.0GB, FETCH +1.7GB, MfmaUtil 3.8%. Relax to
// (256,3): ~170 regs/wave, 3 blocks/CU (12 waves) — same occupancy regime
// as the 874-912 TF m97-structure ladder. Registers bind at 3; LDS (32 KiB)
// would allow 5.
__global__ __launch_bounds__(256, 3) void k_gemm_argmax(
    const uchar* __restrict__ xq, unsigned long long* __restrict__ best,
    int T)
{
    // triangular mapping: p -> (by, bx), bx >= by
    const int p = blockIdx.x;
    const float tf = (float)T + 0.5f;
    int by = (int)(tf - sqrtf(tf * tf - 2.0f * (float)p));
    while (by > 0 && p < by * T - by * (by - 1) / 2) --by;
    while (p >= (by + 1) * T - (by + 1) * by / 2) ++by;
    const int bx = by + (p - (by * T - by * (by - 1) / 2));

    __shared__ uchar lds[2][(BM + BN) * BK];   // 2 x 16 KiB
    const int t    = threadIdx.x;
    const int lane = t & 63;
    const int wave = t >> 6;
    const int r5   = lane & 31;              // row-within-32
    const int h    = lane >> 5;              // k-half selector
    const int wrow = (wave >> 1) * 64;
    const int wcol = (wave & 1) * 64;
    const int m0   = by * BM;
    const int n0   = bx * BN;

    f32x16 acc[2][2] = {};

    // staging: thread t owns stored chunk c = t (rows 0..63) and c = t + 256
    // (rows 64..127) of each panel; stored col = t&3, global col swizzled.
    const int row_s = t >> 2;
    const int col_s = t & 3;
    const int gsw = (col_s ^ ((row_s ^ (row_s >> 2)) & 3)) * 16;  // byte col
    // note swz(row+64) == swz(row), so the same gsw serves both halves
    const uchar* aP0 = xq + (size_t)(m0 + row_s) * 1024 + gsw;
    const uchar* bP0 = xq + (size_t)(n0 + row_s) * 1024 + gsw;
    const uchar* aP1 = aP0 + 64 * 1024;
    const uchar* bP1 = bP0 + 64 * 1024;
    const int l16 = t * 16;

#define STAGE(buf, koff)                                                              \
    do {                                                                              \
        __builtin_amdgcn_global_load_lds(                                             \
            (const __attribute__((address_space(1))) void*)(aP0 + (koff)),            \
            (__attribute__((address_space(3))) void*)(&lds[buf][0] + l16), 16, 0, 0); \
        __builtin_amdgcn_global_load_lds(                                             \
            (const __attribute__((address_space(1))) void*)(aP1 + (koff)),            \
            (__attribute__((address_space(3))) void*)(&lds[buf][4096] + l16), 16, 0, 0); \
        __builtin_amdgcn_global_load_lds(                                             \
            (const __attribute__((address_space(1))) void*)(bP0 + (koff)),            \
            (__attribute__((address_space(3))) void*)(&lds[buf][8192] + l16), 16, 0, 0); \
        __builtin_amdgcn_global_load_lds(                                             \
            (const __attribute__((address_space(1))) void*)(bP1 + (koff)),            \
            (__attribute__((address_space(3))) void*)(&lds[buf][12288] + l16), 16, 0, 0); \
    } while (0)

    STAGE(0, 0);
    __syncthreads();

    // lane-constant LDS read offsets.
    // perm(row) for row = wrow + i*32 + r5 reduces to (r5 ^ (r5>>2)) & 3
    // (wrow, i*32 are multiples of 32 -> drop out of both XOR terms).
    const int psw = (r5 ^ (r5 >> 2)) & 3;
    const int c0  = ((2 * h + 0) ^ psw) * 16;   // first 16B chunk (swizzled)
    const int c1  = ((2 * h + 1) ^ psw) * 16;   // second 16B chunk (swizzled)
    const int aoff0 = (wrow +      r5) * 64;
    const int aoff1 = (wrow + 32 + r5) * 64;
    const int boff0 = (wcol +      r5) * 64;
    const int boff1 = (wcol + 32 + r5) * 64;

    #pragma unroll
    for (int kt = 0; kt < 16; ++kt) {
        const int cur = kt & 1;
        if (kt < 15) STAGE(cur ^ 1, (kt + 1) * BK);   // K-advance in pointer
        const uchar* Al = &lds[cur][0];
        const uchar* Bl = &lds[cur][8192];

        i32x8v bfr[2];
        {
            i32x4v lo0 = *(const i32x4v*)(Bl + boff0 + c0);
            i32x4v hi0 = *(const i32x4v*)(Bl + boff0 + c1);
            bfr[0] = __builtin_shufflevector(lo0, hi0, 0, 1, 2, 3, 4, 5, 6, 7);
            i32x4v lo1 = *(const i32x4v*)(Bl + boff1 + c0);
            i32x4v hi1 = *(const i32x4v*)(Bl + boff1 + c1);
            bfr[1] = __builtin_shufflevector(lo1, hi1, 0, 1, 2, 3, 4, 5, 6, 7);
        }
        #pragma unroll
        for (int i = 0; i < 2; ++i) {
            const uchar* ap = Al + (i ? aoff1 : aoff0);
            i32x4v lo = *(const i32x4v*)(ap + c0);
            i32x4v hi = *(const i32x4v*)(ap + c1);
            i32x8v af = __builtin_shufflevector(lo, hi, 0, 1, 2, 3, 4, 5, 6, 7);
            acc[i][0] = __builtin_amdgcn_mfma_scale_f32_32x32x64_f8f6f4(
                af, bfr[0], acc[i][0], 0, 0, 0, 0x7F, 0, 0x7F);
            acc[i][1] = __builtin_amdgcn_mfma_scale_f32_32x32x64_f8f6f4(
                af, bfr[1], acc[i][1], 0, 0, 0, 0x7F, 0, 0x7F);
        }
        __syncthreads();
    }
#undef STAGE

    // ---- row-wise argmax (this wave's 64 rows, over its 64 cols) ----
    // C/D 32x32 layout: col = lane&31, row = (reg&3) + 8*(reg>>2) + 4*(lane>>5)
    #pragma unroll
    for (int i = 0; i < 2; ++i) {
        #pragma unroll
        for (int r = 0; r < 16; ++r) {
            const int rin  = (r & 3) + 8 * (r >> 2) + 4 * h;
            const int grow = m0 + wrow + i * 32 + rin;
            float v = -3.0f; unsigned c = 0xFFFFFFFFu;
            #pragma unroll
            for (int j = 0; j < 2; ++j) {
                const int col = n0 + wcol + j * 32 + r5;
                const float val = acc[i][j][r];
                if (col != grow && (val > v || (val == v && (unsigned)col < c))) {
                    v = val; c = (unsigned)col;
                }
            }
            // reduce across the 32 lanes of this half-wave (same row)
            for (int off = 16; off; off >>= 1) {
                const float    ov = __shfl_xor(v, off);
                const unsigned oc = (unsigned)__shfl_xor((int)c, off);
                if (ov > v || (ov == v && oc < c)) { v = ov; c = oc; }
            }
            if (r5 == 0) atomicMax(best + grow, pack_key(v, c));
        }
    }

    // ---- col-wise argmax (off-diagonal blocks only) ----
    if (bx != by) {
        #pragma unroll
        for (int j = 0; j < 2; ++j) {
            const int gcol = n0 + wcol + j * 32 + r5;
            float v = -3.0f; unsigned c = 0xFFFFFFFFu;
            #pragma unroll
            for (int i = 0; i < 2; ++i) {
                #pragma unroll
                for (int r = 0; r < 16; ++r) {
                    const int grow = m0 + wrow + i * 32
                                   + (r & 3) + 8 * (r >> 2) + 4 * h;
                    const float val = acc[i][j][r];
                    if (val > v || (val == v && (unsigned)grow < c)) {
                        v = val; c = (unsigned)grow;
                    }
                }
            }
            // merge the two half-waves (same col set, different rows)
            {
                const float    ov = __shfl_xor(v, 32);
                const unsigned oc = (unsigned)__shfl_xor((int)c, 32);
                if (ov > v || (ov == v && oc < c)) { v = ov; c = oc; }
            }
            if (h == 0) atomicMax(best + gcol, pack_key(v, c));
        }
    }
}

// ---------------- 3) pairwise distance + log -> 256 padded partials ---------
__global__ __launch_bounds__(256) void k_dist(
    const float* __restrict__ in, const float* __restrict__ norms,
    const unsigned long long* __restrict__ best, float* __restrict__ psum, int D)
{
    const int row = blockIdx.x;
    const int t = threadIdx.x;
    const unsigned long long key = best[row];
    const int nb = (int)(~(unsigned)key);        // recover neighbor index
    const float invi = 1.0f / fmaxf(norms[row], KEPS);
    const float invj = 1.0f / fmaxf(norms[nb], KEPS);
    const float4* xi = (const float4*)(in + (size_t)row * D);
    const float4* xj = (const float4*)(in + (size_t)nb * D);
    const float4 a = xi[t], b = xj[t];
    const float dx = a.x * invi - b.x * invj + KEPS;
    const float dy = a.y * invi - b.y * invj + KEPS;
    const float dz = a.z * invi - b.z * invj + KEPS;
    const float dw = a.w * invi - b.w * invj + KEPS;
    float ss = dx*dx + dy*dy + dz*dz + dw*dw;
    for (int off = 32; off; off >>= 1) ss += __shfl_down(ss, off);
    __shared__ float red[4];
    const int lane = t & 63, wave = t >> 6;
    if (lane == 0) red[wave] = ss;
    __syncthreads();
    if (t == 0) {
        const float tot = red[0] + red[1] + red[2] + red[3];
        // scatter over 256 cache-line-padded slots: 64 atomics/slot, no hotspot
        atomicAdd(psum + (row & 255) * 16, logf(sqrtf(tot) + KEPS));
    }
}

// ---------------- 4) finalize: reduce 256 partials --------------------------
__global__ void k_final(const float* __restrict__ psum, float* __restrict__ out, float invN)
{
    const int t = threadIdx.x;                   // 64 threads
    float s = psum[t * 16] + psum[(t + 64) * 16]
            + psum[(t + 128) * 16] + psum[(t + 192) * 16];
    for (int off = 32; off; off >>= 1) s += __shfl_down(s, off);
    if (t == 0) out[0] = -s * invN;
}

extern "C" void kernel_launch(void* const* d_in, const int* in_sizes, int n_in,
                              void* d_out, int out_size, void* d_ws, size_t ws_size,
                              hipStream_t stream)
{
    const float* in = (const float*)d_in[0];
    const int D = 1024;
    const int N = in_sizes[0] / D;               // 16384

    char* ws = (char*)d_ws;
    uchar* xq = (uchar*)ws;                                      // N*D = 16 MiB
    size_t off = (size_t)N * D;
    float* norms = (float*)(ws + off);           off += (size_t)N * 4;
    unsigned long long* best = (unsigned long long*)(ws + off); off += (size_t)N * 8;
    float* psum = (float*)(ws + off);            // 256 slots x 16 floats
    float* out = (float*)d_out;

    k_normalize<<<N, 256, 0, stream>>>(in, xq, norms, best, psum, D);
    const int T = N / BM;                        // 128 tiles per dim
    const int P = T * (T + 1) / 2;               // 8256 upper-tri blocks
    k_gemm_argmax<<<P, 256, 0, stream>>>(xq, best, T);
    k_dist<<<N, 256, 0, stream>>>(in, norms, best, psum, D);
    k_final<<<1, 64, 0, stream>>>(psum, out, 1.0f / (float)N);
}